// Round 3
// baseline (174.887 us; speedup 1.0000x reference)
//
#include <hip/hip_runtime.h>
#include <math.h>

#define M_ 4
#define A_ 256
#define RBF_ 64
#define F_ 32
#define H_ 32
#define SI_ 32
#define TF_ 128   // 4 tags * F

typedef __attribute__((ext_vector_type(8))) short bf16x8;
typedef __attribute__((ext_vector_type(4))) float f32x4;
typedef __attribute__((ext_vector_type(3))) float f32x3;

__device__ __forceinline__ unsigned short f2bf(float f) {
  union { float f; unsigned u; } v; v.f = f;
  unsigned r = v.u + 0x7FFFu + ((v.u >> 16) & 1u);   // RNE bf16 (weights, one-time)
  return (unsigned short)(r >> 16);
}

// pack two fp32 -> two bf16 (round-half-up: +0x8000 then take hi16) in 3 VALU
__device__ __forceinline__ unsigned pack2bf(float lo, float hi) {
  union { float f; unsigned u; } a, b; a.f = lo; b.f = hi;
  return __builtin_amdgcn_perm(b.u + 0x8000u, a.u + 0x8000u, 0x07060302u);
}

__device__ __forceinline__ float sspf(float x) {
  // log(0.5*exp(x)+0.5) = softplus(x) - ln2, numerically stable
  return fmaxf(x, 0.f) + log1pf(expf(-fabsf(x))) - 0.6931471805599453f;
}

// ---------------------------------------------------------------------------
// Setup: collapse the two linear Dense layers per tag into one 64x32 map.
// ws layout: WcT bf16 [tf=128][k=64] (16384 B) | bc fp32[128] at +16384.
// tf = tag*32 + f, tag order {00,01,10,11}.
// ---------------------------------------------------------------------------
__global__ __launch_bounds__(256) void combine_weights(
    const float* __restrict__ w1_00, const float* __restrict__ b1_00,
    const float* __restrict__ w2_00, const float* __restrict__ b2_00,
    const float* __restrict__ w1_01, const float* __restrict__ b1_01,
    const float* __restrict__ w2_01, const float* __restrict__ b2_01,
    const float* __restrict__ w1_10, const float* __restrict__ b1_10,
    const float* __restrict__ w2_10, const float* __restrict__ b2_10,
    const float* __restrict__ w1_11, const float* __restrict__ b1_11,
    const float* __restrict__ w2_11, const float* __restrict__ b2_11,
    unsigned short* __restrict__ wsT, float* __restrict__ bcw)
{
  const float* w1s[4] = {w1_00, w1_01, w1_10, w1_11};
  const float* b1s[4] = {b1_00, b1_01, b1_10, b1_11};
  const float* w2s[4] = {w2_00, w2_01, w2_10, w2_11};
  const float* b2s[4] = {b2_00, b2_01, b2_10, b2_11};
  int tid = blockIdx.x * 256 + threadIdx.x;    // 0..8191
  int k   = tid >> 7;
  int tf  = tid & 127;
  int tag = tf >> 5, f = tf & 31;
  const float* w1 = w1s[tag];
  const float* w2 = w2s[tag];
  float s = 0.f;
  for (int h = 0; h < H_; ++h) s += w1[k * H_ + h] * w2[h * F_ + f];
  wsT[tf * 64 + k] = f2bf(s);                  // transposed for B-frag loads
  if (tid < TF_) {
    const float* b1 = b1s[tag];
    const float* b2 = b2s[tag];
    float sb = b2[f];
    for (int h = 0; h < H_; ++h) sb += b1[h] * w2[h * F_ + f];
    bcw[tf] = sb;                              // bias stays fp32
  }
}

// ---------------------------------------------------------------------------
// R14 FUSED kernel: one block per (m,a), grid 1024, 512 thr, 8 waves,
// wave-per-(tag,f-half) role as R13. Staging structure = R13 (proven):
// H1 prologue + H2 one-float4-in-flight stream, 2 lgkm-only barriers.
//  R14 change: SOFTWARE-PIPELINED tile loop. R0/R12/R13 all sat at 41-47us
//  with VALUBusy ~29% -- the per-tile serial chain {ds_read a-frag (120cy)
//  -> MFMA (~40cy) -> VALU contract (~150cy)} x16, phase-correlated across
//  waves, was the limiter. Now per half-iter:
//    MFMA(tile T) ; ds_read(T+1)->aF ; CONTRACT(T-1) ; PF feat(T+1)
//  so every consumer is >=1 half-iter (~110+ cyc) from its producer:
//  ds latency, MFMA latency, and feat-L2 latency all off the critical path.
//  Two 8-tile pipelined segments (A: tiles 0-7 + H2 pack interleave, B: 8-15).
//  LDS: sA [256][72] bf16 (36864) + sV[768] f32 (3072, cat overlays) = 39936.
//  Sentinels: VGPR <= 64 (else 4 blocks/CU lost); WRITE_SIZE ~512 KB (spill).
// ---------------------------------------------------------------------------
__global__ __launch_bounds__(512, 4) void conv_fused(
    const float* __restrict__ image, const float* __restrict__ vectors,
    const float* __restrict__ feat0, const float* __restrict__ feat1,
    const unsigned short* __restrict__ wsT, const float* __restrict__ bcw,
    const float* __restrict__ w_si0, const float* __restrict__ w_si1,
    const float* __restrict__ b_act0, const float* __restrict__ b_act1,
    float* __restrict__ out)
{
  __shared__ __align__(16) unsigned short sA[256 * 72];    // 36864 B
  __shared__ __align__(16) float sV[A_ * 3];               // 3072 B (cat overlays)
  float* const cat = sV;                                   // reused after sync

  const int t    = threadIdx.x;
  const int ma   = blockIdx.x;      // m*256 + a
  const int m    = ma >> 8;
  const int l    = t & 63;
  const int n    = l & 15;
  const int quad = l >> 4;
  // wave id as SGPR -> uniform branches; rotate roles across SIMDs per block
  const int wu    = __builtin_amdgcn_readfirstlane(t >> 6);   // 0..7
  const int role  = (wu + ((ma & 3) << 1)) & 7;
  const int which = role & 1;
  const int tag   = role >> 1;      // 0:'00' 1:'01' 2:'10' 3:'11'
  const int ct    = tag * 2 + which;
  const int f     = which * 16 + n; // feature column this lane owns

  // ---- Wc fragment + bias into registers (global, L2-resident) ----
  const unsigned short* wr = wsT + (ct * 16 + n) * 64 + quad * 8;
  const bf16x8 w0 = *(const bf16x8*)(wr);
  const bf16x8 w1 = *(const bf16x8*)(wr + 32);
  const float  bc = bcw[ct * 16 + n];

  // ---- stage addressing: thread t owns row t>>2 (0..127), cols (t&3)*16 ----
  const int srow = t >> 2;
  const int sc16 = (t & 3) << 4;
  const float* g1 = image + (size_t)ma * (A_ * RBF_) + srow * RBF_ + sc16;
  const float* g2 = g1 + 128 * RBF_;                 // H2 source (rows +128)
  unsigned short* w1p = &sA[srow * 72 + sc16];
  unsigned short* w2p = &sA[(srow + 128) * 72 + sc16];

  // ---- H1: 4 float4 loads, pack, two b128 LDS writes ----
  float4 a0 = *(const float4*)(g1);
  float4 a1 = *(const float4*)(g1 + 4);
  float4 a2 = *(const float4*)(g1 + 8);
  float4 a3 = *(const float4*)(g1 + 12);
  // ---- stage vectors (256 b x 3) to LDS ----
  {
    const float* vsrc = vectors + (size_t)ma * (A_ * 3);
    sV[t] = vsrc[t];
    if (t < 256) sV[t + 512] = vsrc[t + 512];
  }
  {
    uint4 pk;
    pk.x = pack2bf(a0.x, a0.y); pk.y = pack2bf(a0.z, a0.w);
    pk.z = pack2bf(a1.x, a1.y); pk.w = pack2bf(a1.z, a1.w);
    *(uint4*)w1p = pk;
    pk.x = pack2bf(a2.x, a2.y); pk.y = pack2bf(a2.z, a2.w);
    pk.z = pack2bf(a3.x, a3.y); pk.w = pack2bf(a3.z, a3.w);
    *(uint4*)(w1p + 8) = pk;
  }
  // first H2 quarter in flight across the barrier
  float4 hb = *(const float4*)(g2);

  // ---- running feat pointers (advanced by constants; imm-offset loads) ----
  const int b0q = quad * 4;
  const float* p0c = feat0 + (size_t)(m * A_ + b0q) * F_ + f;       // feat0 col
  const float* p1c = feat1 + ((size_t)(m * A_ + b0q) * F_ + f) * 3; // feat1 col
  const float* svc = &sV[b0q * 3];
  const unsigned short* aBc = &sA[n * 72 + quad * 8];

  float gx[2][4], gy[2][4], gz[2][4];
  float pA = 0.f, pB0 = 0.f, pB1 = 0.f, pB2 = 0.f;
  bf16x8 aFa, aFb;          // single-tile frag pair, read one tile ahead
  f32x4 accA, accB;         // double accumulator: contract deferred 1 half-iter

#define PF(BUF) { \
    if (tag <= 1) { \
      _Pragma("unroll") \
      for (int r = 0; r < 4; ++r) gx[BUF][r] = p0c[r * F_]; \
    } else { \
      _Pragma("unroll") \
      for (int r = 0; r < 4; ++r) { \
        f32x3 v = *(const f32x3*)(p1c + r * (F_ * 3)); \
        gx[BUF][r] = v[0]; gy[BUF][r] = v[1]; gz[BUF][r] = v[2]; \
      } \
    } \
    p0c += 16 * F_; p1c += 16 * F_ * 3; }

  // read next tile's A-frags into the (just-consumed) frag pair
#define DSRD() { \
    aFa = *(const bf16x8*)(aBc); \
    aFb = *(const bf16x8*)(aBc + 32); \
    aBc += 1152; }

  // two MFMAs of the current tile into ACC (bias pre-seeded)
#define MF(ACC) { \
    ACC = (f32x4){bc, bc, bc, bc}; \
    ACC = __builtin_amdgcn_mfma_f32_16x16x32_bf16(aFa, w0, ACC, 0, 0, 0); \
    ACC = __builtin_amdgcn_mfma_f32_16x16x32_bf16(aFb, w1, ACC, 0, 0, 0); }

  // tag-specific contraction of a finished tile's R values
#define CONTRACT(ACC, SOFF, GX, GY, GZ) { \
    if (tag == 0) {            /* out_0x0_0 */ \
      _Pragma("unroll") \
      for (int r = 0; r < 4; ++r) pA += ACC[r] * GX[r]; \
    } else if (tag == 1) {     /* out_0x1_1 = v * (R*feat0) */ \
      _Pragma("unroll") \
      for (int r = 0; r < 4; ++r) { \
        const float s = ACC[r] * GX[r]; \
        pB0 += svc[(SOFF) + r * 3 + 0] * s; \
        pB1 += svc[(SOFF) + r * 3 + 1] * s; \
        pB2 += svc[(SOFF) + r * 3 + 2] * s; \
      } \
    } else if (tag == 2) {     /* out_1x0_1 = R * feat1 */ \
      _Pragma("unroll") \
      for (int r = 0; r < 4; ++r) { \
        const float Rr = ACC[r]; \
        pB0 += Rr * GX[r]; pB1 += Rr * GY[r]; pB2 += Rr * GZ[r]; \
      } \
    } else {                   /* out_1x1_0 (dot) + out_1x1_1 (cross) */ \
      _Pragma("unroll") \
      for (int r = 0; r < 4; ++r) { \
        const float Rr = ACC[r]; \
        const float ax = GX[r], ay = GY[r], az = GZ[r]; \
        const float vx = svc[(SOFF) + r * 3 + 0]; \
        const float vy = svc[(SOFF) + r * 3 + 1]; \
        const float vz = svc[(SOFF) + r * 3 + 2]; \
        float d = vx * ax; d = fmaf(vy, ay, d); d = fmaf(vz, az, d); \
        pA = fmaf(Rr, d, pA); \
        float c0 = vy * az; c0 = fmaf(-vz, ay, c0); pB0 = fmaf(Rr, c0, pB0); \
        float c1 = vz * ax; c1 = fmaf(-vx, az, c1); pB1 = fmaf(Rr, c1, pB1); \
        float c2 = vx * ay; c2 = fmaf(-vy, ax, c2); pB2 = fmaf(Rr, c2, pB2); \
      } \
    } }

  // H2 stream: pack the in-flight quarter, (optionally) issue the next
#define H2PACK_R() { \
    uint2 pk; pk.x = pack2bf(hb.x, hb.y); pk.y = pack2bf(hb.z, hb.w); \
    *(uint2*)w2p = pk; w2p += 4; \
    g2 += 4; hb = *(const float4*)(g2); }
#define H2PACK_F() { \
    uint2 pk; pk.x = pack2bf(hb.x, hb.y); pk.y = pack2bf(hb.z, hb.w); \
    *(uint2*)w2p = pk; }

  // lgkm-only barrier: ds ops drained, global loads STAY IN FLIGHT.
#define BARRIER() { \
    asm volatile("s_waitcnt lgkmcnt(0)" ::: "memory"); \
    __builtin_amdgcn_s_barrier(); \
    asm volatile("" ::: "memory"); }

  // ================= segment A: tiles 0..7 (H1), H2 stream ================
  PF(0)                                 // feat t0 (in flight over barrier)
  BARRIER();
  DSRD()                                // t0 -> aF
  PF(1)                                 // feat t1
  MF(accA)                              // t0
  DSRD()                                // t1 -> aF

  #pragma unroll 1
  for (int d = 0; d < 3; ++d) {
    MF(accB)                                            // tile 2d+1
    DSRD()                                              // -> tile 2d+2
    CONTRACT(accA, 0, gx[0], gy[0], gz[0])              // tile 2d
    PF(0)                                               // feat tile 2d+2
    MF(accA)                                            // tile 2d+2
    DSRD()                                              // -> tile 2d+3
    CONTRACT(accB, 48, gx[1], gy[1], gz[1])             // tile 2d+1
    PF(1)                                               // feat tile 2d+3
    H2PACK_R()                                          // H2 quarter d
    svc += 96;
  }
  MF(accB)                                              // t7
  CONTRACT(accA, 0, gx[0], gy[0], gz[0])                // t6
  CONTRACT(accB, 48, gx[1], gy[1], gz[1])               // t7
  svc += 96;
  H2PACK_F()                                            // H2 quarter 3
  BARRIER();                            // H2 writes drained; rows 128+ ready

  // ================= segment B: tiles 8..15 ================
  PF(0)                                 // feat t8
  DSRD()                                // t8 -> aF
  PF(1)                                 // feat t9
  MF(accA)                              // t8
  DSRD()                                // t9 -> aF

  #pragma unroll 1
  for (int d = 0; d < 3; ++d) {
    MF(accB)                                            // tile 2d+9
    DSRD()                                              // -> tile 2d+10
    CONTRACT(accA, 0, gx[0], gy[0], gz[0])              // tile 2d+8
    PF(0)                                               // feat tile 2d+10
    MF(accA)                                            // tile 2d+10
    DSRD()                                              // -> tile 2d+11
    CONTRACT(accB, 48, gx[1], gy[1], gz[1])             // tile 2d+9
    PF(1)                                               // feat tile 2d+11
    svc += 96;
  }
  MF(accB)                                              // t15
  CONTRACT(accA, 0, gx[0], gy[0], gz[0])                // t14
  CONTRACT(accB, 48, gx[1], gy[1], gz[1])               // t15

  // ---- reduce the 4 quad-copies ----
#define QRED(x) { x += __shfl_xor(x, 16); x += __shfl_xor(x, 32); }
  QRED(pA) QRED(pB0) QRED(pB1) QRED(pB2)
  __syncthreads();            // all sV reads done (cat overlays sV)
  if (quad == 0) {
    // slots (cat order): out000: f | out110: 32+f | out011: 64+f*3+d
    //                    out101: 160+f*3+d | out111: 256+f*3+d
    if (tag == 0) {
      cat[f] = pA;
    } else if (tag == 1) {
      cat[64 + f * 3 + 0] = pB0; cat[64 + f * 3 + 1] = pB1; cat[64 + f * 3 + 2] = pB2;
    } else if (tag == 2) {
      cat[160 + f * 3 + 0] = pB0; cat[160 + f * 3 + 1] = pB1; cat[160 + f * 3 + 2] = pB2;
    } else {
      cat[32 + f] = pA;
      cat[256 + f * 3 + 0] = pB0; cat[256 + f * 3 + 1] = pB1; cat[256 + f * 3 + 2] = pB2;
    }
  }
  __syncthreads();            // cat visible to all

  // ---- fused self-interaction + equivariant activation ----
  if (t < 256) {
    // SI1: 32 outputs x 3 comps; 8 lanes per output, 12 ff-terms each
    const int g = t >> 3, p = t & 7;
    const float* wrow = w_si1 + g * 96 + p * 12;
    const float* c1 = &cat[64 + p * 36];
    float s0 = 0.f, s1 = 0.f, s2 = 0.f;
    #pragma unroll
    for (int k = 0; k < 12; ++k) {
      const float wv = wrow[k];
      s0 = fmaf(c1[k * 3 + 0], wv, s0);
      s1 = fmaf(c1[k * 3 + 1], wv, s1);
      s2 = fmaf(c1[k * 3 + 2], wv, s2);
    }
    s0 += __shfl_xor(s0, 1); s0 += __shfl_xor(s0, 2); s0 += __shfl_xor(s0, 4);
    s1 += __shfl_xor(s1, 1); s1 += __shfl_xor(s1, 2); s1 += __shfl_xor(s1, 4);
    s2 += __shfl_xor(s2, 1); s2 += __shfl_xor(s2, 2); s2 += __shfl_xor(s2, 4);
    if (p == 0) {
      const float n2 = s0 * s0 + s1 * s1 + s2 * s2;
      const float n1 = sqrtf(fmaxf(n2, 1e-7f));     // norm_with_epsilon
      const float a1 = sspf(n1 + b_act1[g]);
      const float sc = a1 / n1;
      const int ob = M_ * A_ * SI_ + (ma * SI_ + g) * 3;
      out[ob + 0] = s0 * sc; out[ob + 1] = s1 * sc; out[ob + 2] = s2 * sc;
    }
  } else if (t < 320) {
    // SI0: 32 outputs; 2 lanes per output, 32 ff-terms each (wave 4 only)
    const int t2 = t - 256, g = t2 >> 1, p = t2 & 1;
    const float* wrow = w_si0 + g * 64 + p * 32;
    const float* c0 = &cat[p * 32];
    float s = 0.f;
    #pragma unroll 8
    for (int k = 0; k < 32; ++k) s = fmaf(c0[k], wrow[k], s);
    s += __shfl_xor(s, 1);
    if (p == 0) out[ma * SI_ + g] = sspf(s + b_act0[g]);
  }
}

extern "C" void kernel_launch(void* const* d_in, const int* in_sizes, int n_in,
                              void* d_out, int out_size, void* d_ws, size_t ws_size,
                              hipStream_t stream) {
  const float* image   = (const float*)d_in[0];
  const float* vectors = (const float*)d_in[1];
  const float* feat0   = (const float*)d_in[2];
  const float* feat1   = (const float*)d_in[3];
  const float* w_si0   = (const float*)d_in[20];
  const float* w_si1   = (const float*)d_in[21];
  const float* b_act0  = (const float*)d_in[22];
  const float* b_act1  = (const float*)d_in[23];
  unsigned short* wsT = (unsigned short*)d_ws;           // 128*64 bf16 = 16384 B
  float* bcw  = (float*)((char*)d_ws + 16384);           // 128 f32
  float* out  = (float*)d_out;

  combine_weights<<<32, 256, 0, stream>>>(
      (const float*)d_in[4],  (const float*)d_in[5],
      (const float*)d_in[6],  (const float*)d_in[7],
      (const float*)d_in[8],  (const float*)d_in[9],
      (const float*)d_in[10], (const float*)d_in[11],
      (const float*)d_in[12], (const float*)d_in[13],
      (const float*)d_in[14], (const float*)d_in[15],
      (const float*)d_in[16], (const float*)d_in[17],
      (const float*)d_in[18], (const float*)d_in[19],
      wsT, bcw);

  conv_fused<<<M_ * A_, 512, 0, stream>>>(
      image, vectors, feat0, feat1, wsT, bcw,
      w_si0, w_si1, b_act0, b_act1, out);
}

// Round 4
// 165.345 us; speedup vs baseline: 1.0577x; 1.0577x over previous
//
#include <hip/hip_runtime.h>
#include <math.h>

#define M_ 4
#define A_ 256
#define RBF_ 64
#define F_ 32
#define H_ 32
#define SI_ 32
#define TF_ 128   // 4 tags * F

typedef __attribute__((ext_vector_type(8))) short bf16x8;
typedef __attribute__((ext_vector_type(4))) float f32x4;
typedef __attribute__((ext_vector_type(3))) float f32x3;

__device__ __forceinline__ unsigned short f2bf(float f) {
  union { float f; unsigned u; } v; v.f = f;
  unsigned r = v.u + 0x7FFFu + ((v.u >> 16) & 1u);   // RNE bf16 (weights, one-time)
  return (unsigned short)(r >> 16);
}

// pack two fp32 -> two bf16 (round-half-up: +0x8000 then take hi16) in 3 VALU
__device__ __forceinline__ unsigned pack2bf(float lo, float hi) {
  union { float f; unsigned u; } a, b; a.f = lo; b.f = hi;
  return __builtin_amdgcn_perm(b.u + 0x8000u, a.u + 0x8000u, 0x07060302u);
}

__device__ __forceinline__ float sspf(float x) {
  // log(0.5*exp(x)+0.5) = softplus(x) - ln2, numerically stable
  return fmaxf(x, 0.f) + log1pf(expf(-fabsf(x))) - 0.6931471805599453f;
}

// ---------------------------------------------------------------------------
// Setup: collapse the two linear Dense layers per tag into one 64x32 map.
// ws layout: WcT bf16 [tf=128][k=64] (16384 B) | bc fp32[128] at +16384.
// tf = tag*32 + f, tag order {00,01,10,11}.
// ---------------------------------------------------------------------------
__global__ __launch_bounds__(256) void combine_weights(
    const float* __restrict__ w1_00, const float* __restrict__ b1_00,
    const float* __restrict__ w2_00, const float* __restrict__ b2_00,
    const float* __restrict__ w1_01, const float* __restrict__ b1_01,
    const float* __restrict__ w2_01, const float* __restrict__ b2_01,
    const float* __restrict__ w1_10, const float* __restrict__ b1_10,
    const float* __restrict__ w2_10, const float* __restrict__ b2_10,
    const float* __restrict__ w1_11, const float* __restrict__ b1_11,
    const float* __restrict__ w2_11, const float* __restrict__ b2_11,
    unsigned short* __restrict__ wsT, float* __restrict__ bcw)
{
  const float* w1s[4] = {w1_00, w1_01, w1_10, w1_11};
  const float* b1s[4] = {b1_00, b1_01, b1_10, b1_11};
  const float* w2s[4] = {w2_00, w2_01, w2_10, w2_11};
  const float* b2s[4] = {b2_00, b2_01, b2_10, b2_11};
  int tid = blockIdx.x * 256 + threadIdx.x;    // 0..8191
  int k   = tid >> 7;
  int tf  = tid & 127;
  int tag = tf >> 5, f = tf & 31;
  const float* w1 = w1s[tag];
  const float* w2 = w2s[tag];
  float s = 0.f;
  for (int h = 0; h < H_; ++h) s += w1[k * H_ + h] * w2[h * F_ + f];
  wsT[tf * 64 + k] = f2bf(s);                  // transposed for B-frag loads
  if (tid < TF_) {
    const float* b1 = b1s[tag];
    const float* b2 = b2s[tag];
    float sb = b2[f];
    for (int h = 0; h < H_; ++h) sb += b1[h] * w2[h * F_ + f];
    bcw[tf] = sb;                              // bias stays fp32
  }
}

// ---------------------------------------------------------------------------
// R15 FUSED kernel: one block per (m,a), grid 1024, 512 thr, 8 waves,
// wave-per-(tag,f-half) role as R13. Staging structure = R13 (proven):
// H1 prologue + H2 one-float4-in-flight stream, 2 lgkm-only barriers.
//  Post-mortem R14 (65us): full pipeline (acc dbuf + frag dbuf) blew the
//  64-VGPR budget at (512,4) -> 18.9 MB scratch writes. The scheduling idea
//  was never tested.
//  R15 = R13 + the ONE cheapest pipeline element: cross-tile a-frag
//  prefetch (unroll-2, two named frag pairs, +8 VGPR -> ~56). All 8 waves
//  leave the same barrier and run identical {lgkm-wait(frag)->MFMA->
//  contract} chains -> phase-locked convoy on the LDS wait. Issuing tile
//  T+1's two ds_read_b128 BEFORE tile T's MFMA+contract gives each wave a
//  ~300cy runnable stretch per tile (no memory wait), so SIMD round-robin
//  can fill. acc stays single (MFMA latency is the cheap link). Segment B's
//  first feat load hoisted above the H2 barrier (globals fly across it).
//  LDS: sA [256][72] bf16 (36864) + sV[768] f32 (3072, cat overlays) = 39936.
//  Sentinels: VGPR <= 64 (else occupancy lost); WRITE_SIZE ~512 KB (spill).
// ---------------------------------------------------------------------------
__global__ __launch_bounds__(512, 4) void conv_fused(
    const float* __restrict__ image, const float* __restrict__ vectors,
    const float* __restrict__ feat0, const float* __restrict__ feat1,
    const unsigned short* __restrict__ wsT, const float* __restrict__ bcw,
    const float* __restrict__ w_si0, const float* __restrict__ w_si1,
    const float* __restrict__ b_act0, const float* __restrict__ b_act1,
    float* __restrict__ out)
{
  __shared__ __align__(16) unsigned short sA[256 * 72];    // 36864 B
  __shared__ __align__(16) float sV[A_ * 3];               // 3072 B (cat overlays)
  float* const cat = sV;                                   // reused after sync

  const int t    = threadIdx.x;
  const int ma   = blockIdx.x;      // m*256 + a
  const int m    = ma >> 8;
  const int l    = t & 63;
  const int n    = l & 15;
  const int quad = l >> 4;
  // wave id as SGPR -> uniform branches; rotate roles across SIMDs per block
  const int wu    = __builtin_amdgcn_readfirstlane(t >> 6);   // 0..7
  const int role  = (wu + ((ma & 3) << 1)) & 7;
  const int which = role & 1;
  const int tag   = role >> 1;      // 0:'00' 1:'01' 2:'10' 3:'11'
  const int ct    = tag * 2 + which;
  const int f     = which * 16 + n; // feature column this lane owns

  // ---- Wc fragment + bias into registers (global, L2-resident) ----
  const unsigned short* wr = wsT + (ct * 16 + n) * 64 + quad * 8;
  const bf16x8 w0 = *(const bf16x8*)(wr);
  const bf16x8 w1 = *(const bf16x8*)(wr + 32);
  const float  bc = bcw[ct * 16 + n];

  // ---- stage addressing: thread t owns row t>>2 (0..127), cols (t&3)*16 ----
  const int srow = t >> 2;
  const int sc16 = (t & 3) << 4;
  const float* g1 = image + (size_t)ma * (A_ * RBF_) + srow * RBF_ + sc16;
  const float* g2 = g1 + 128 * RBF_;                 // H2 source (rows +128)
  unsigned short* w1p = &sA[srow * 72 + sc16];
  unsigned short* w2p = &sA[(srow + 128) * 72 + sc16];

  // ---- H1: 4 float4 loads, pack, two b128 LDS writes ----
  float4 a0 = *(const float4*)(g1);
  float4 a1 = *(const float4*)(g1 + 4);
  float4 a2 = *(const float4*)(g1 + 8);
  float4 a3 = *(const float4*)(g1 + 12);
  // ---- stage vectors (256 b x 3) to LDS ----
  {
    const float* vsrc = vectors + (size_t)ma * (A_ * 3);
    sV[t] = vsrc[t];
    if (t < 256) sV[t + 512] = vsrc[t + 512];
  }
  {
    uint4 pk;
    pk.x = pack2bf(a0.x, a0.y); pk.y = pack2bf(a0.z, a0.w);
    pk.z = pack2bf(a1.x, a1.y); pk.w = pack2bf(a1.z, a1.w);
    *(uint4*)w1p = pk;
    pk.x = pack2bf(a2.x, a2.y); pk.y = pack2bf(a2.z, a2.w);
    pk.z = pack2bf(a3.x, a3.y); pk.w = pack2bf(a3.z, a3.w);
    *(uint4*)(w1p + 8) = pk;
  }
  // first H2 quarter in flight across the barrier
  float4 hb = *(const float4*)(g2);

  // ---- running feat pointers (advanced by constants; imm-offset loads) ----
  const int b0q = quad * 4;
  const float* p0c = feat0 + (size_t)(m * A_ + b0q) * F_ + f;       // feat0 col
  const float* p1c = feat1 + ((size_t)(m * A_ + b0q) * F_ + f) * 3; // feat1 col
  const float* svc = &sV[b0q * 3];
  const unsigned short* aBc = &sA[n * 72 + quad * 8];

  float gx[2][4], gy[2][4], gz[2][4];
  float pA = 0.f, pB0 = 0.f, pB1 = 0.f, pB2 = 0.f;
  bf16x8 aF0a, aF0b, aF1a, aF1b;   // two named frag pairs (even/odd tiles)

#define PF(BUF) { \
    if (tag <= 1) { \
      _Pragma("unroll") \
      for (int r = 0; r < 4; ++r) gx[BUF][r] = p0c[r * F_]; \
    } else { \
      _Pragma("unroll") \
      for (int r = 0; r < 4; ++r) { \
        f32x3 v = *(const f32x3*)(p1c + r * (F_ * 3)); \
        gx[BUF][r] = v[0]; gy[BUF][r] = v[1]; gz[BUF][r] = v[2]; \
      } \
    } \
    p0c += 16 * F_; p1c += 16 * F_ * 3; }

  // read the NEXT tile's A-frags into a named pair; advance tile base
#define DSRD(A0, A1) { \
    A0 = *(const bf16x8*)(aBc); \
    A1 = *(const bf16x8*)(aBc + 32); \
    aBc += 1152; }

  // MFMA the given frag pair (bias pre-seeded) then contract immediately
#define MFC(A0, A1, SOFF, GX, GY, GZ) { \
    f32x4 acc = {bc, bc, bc, bc}; \
    acc = __builtin_amdgcn_mfma_f32_16x16x32_bf16(A0, w0, acc, 0, 0, 0); \
    acc = __builtin_amdgcn_mfma_f32_16x16x32_bf16(A1, w1, acc, 0, 0, 0); \
    if (tag == 0) {            /* out_0x0_0 */ \
      _Pragma("unroll") \
      for (int r = 0; r < 4; ++r) pA += acc[r] * GX[r]; \
    } else if (tag == 1) {     /* out_0x1_1 = v * (R*feat0) */ \
      _Pragma("unroll") \
      for (int r = 0; r < 4; ++r) { \
        const float s = acc[r] * GX[r]; \
        pB0 += svc[(SOFF) + r * 3 + 0] * s; \
        pB1 += svc[(SOFF) + r * 3 + 1] * s; \
        pB2 += svc[(SOFF) + r * 3 + 2] * s; \
      } \
    } else if (tag == 2) {     /* out_1x0_1 = R * feat1 */ \
      _Pragma("unroll") \
      for (int r = 0; r < 4; ++r) { \
        const float Rr = acc[r]; \
        pB0 += Rr * GX[r]; pB1 += Rr * GY[r]; pB2 += Rr * GZ[r]; \
      } \
    } else {                   /* out_1x1_0 (dot) + out_1x1_1 (cross) */ \
      _Pragma("unroll") \
      for (int r = 0; r < 4; ++r) { \
        const float Rr = acc[r]; \
        const float ax = GX[r], ay = GY[r], az = GZ[r]; \
        const float vx = svc[(SOFF) + r * 3 + 0]; \
        const float vy = svc[(SOFF) + r * 3 + 1]; \
        const float vz = svc[(SOFF) + r * 3 + 2]; \
        float d = vx * ax; d = fmaf(vy, ay, d); d = fmaf(vz, az, d); \
        pA = fmaf(Rr, d, pA); \
        float c0 = vy * az; c0 = fmaf(-vz, ay, c0); pB0 = fmaf(Rr, c0, pB0); \
        float c1 = vz * ax; c1 = fmaf(-vx, az, c1); pB1 = fmaf(Rr, c1, pB1); \
        float c2 = vx * ay; c2 = fmaf(-vy, ax, c2); pB2 = fmaf(Rr, c2, pB2); \
      } \
    } }

  // H2 stream: pack the in-flight quarter, (optionally) issue the next
#define H2PACK_R() { \
    uint2 pk; pk.x = pack2bf(hb.x, hb.y); pk.y = pack2bf(hb.z, hb.w); \
    *(uint2*)w2p = pk; w2p += 4; \
    g2 += 4; hb = *(const float4*)(g2); }
#define H2PACK_F() { \
    uint2 pk; pk.x = pack2bf(hb.x, hb.y); pk.y = pack2bf(hb.z, hb.w); \
    *(uint2*)w2p = pk; }

  // lgkm-only barrier: ds ops drained, global loads STAY IN FLIGHT.
#define BARRIER() { \
    asm volatile("s_waitcnt lgkmcnt(0)" ::: "memory"); \
    __builtin_amdgcn_s_barrier(); \
    asm volatile("" ::: "memory"); }

  // ================= segment A: tiles 0..7 (H1), H2 stream ================
  PF(0)                                 // feat t0 (in flight over barrier)
  BARRIER();
  DSRD(aF0a, aF0b)                      // t0 -> aF0
  PF(1)                                 // feat t1

  #pragma unroll 1
  for (int d = 0; d < 3; ++d) {
    DSRD(aF1a, aF1b)                            // t(2d+1) -> aF1 (early)
    MFC(aF0a, aF0b, 0, gx[0], gy[0], gz[0])     // tile 2d
    PF(0)                                       // feat t(2d+2)
    DSRD(aF0a, aF0b)                            // t(2d+2) -> aF0 (early)
    MFC(aF1a, aF1b, 48, gx[1], gy[1], gz[1])    // tile 2d+1
    PF(1)                                       // feat t(2d+3)
    H2PACK_R()                                  // H2 quarter d
    svc += 96;
  }
  DSRD(aF1a, aF1b)                              // t7 -> aF1
  MFC(aF0a, aF0b, 0, gx[0], gy[0], gz[0])       // t6
  MFC(aF1a, aF1b, 48, gx[1], gy[1], gz[1])      // t7
  svc += 96;
  H2PACK_F()                                    // H2 quarter 3
  PF(0)                                         // feat t8 (flies over barrier)
  BARRIER();                            // H2 writes drained; rows 128+ ready

  // ================= segment B: tiles 8..15 ================
  DSRD(aF0a, aF0b)                      // t8 -> aF0
  PF(1)                                 // feat t9

  #pragma unroll 1
  for (int d = 0; d < 3; ++d) {
    DSRD(aF1a, aF1b)                            // t(2d+9) -> aF1 (early)
    MFC(aF0a, aF0b, 0, gx[0], gy[0], gz[0])     // tile 2d+8
    PF(0)                                       // feat t(2d+10)
    DSRD(aF0a, aF0b)                            // t(2d+10) -> aF0 (early)
    MFC(aF1a, aF1b, 48, gx[1], gy[1], gz[1])    // tile 2d+9
    PF(1)                                       // feat t(2d+11)
    svc += 96;
  }
  DSRD(aF1a, aF1b)                              // t15 -> aF1
  MFC(aF0a, aF0b, 0, gx[0], gy[0], gz[0])       // t14
  MFC(aF1a, aF1b, 48, gx[1], gy[1], gz[1])      // t15

  // ---- reduce the 4 quad-copies ----
#define QRED(x) { x += __shfl_xor(x, 16); x += __shfl_xor(x, 32); }
  QRED(pA) QRED(pB0) QRED(pB1) QRED(pB2)
  __syncthreads();            // all sV reads done (cat overlays sV)
  if (quad == 0) {
    // slots (cat order): out000: f | out110: 32+f | out011: 64+f*3+d
    //                    out101: 160+f*3+d | out111: 256+f*3+d
    if (tag == 0) {
      cat[f] = pA;
    } else if (tag == 1) {
      cat[64 + f * 3 + 0] = pB0; cat[64 + f * 3 + 1] = pB1; cat[64 + f * 3 + 2] = pB2;
    } else if (tag == 2) {
      cat[160 + f * 3 + 0] = pB0; cat[160 + f * 3 + 1] = pB1; cat[160 + f * 3 + 2] = pB2;
    } else {
      cat[32 + f] = pA;
      cat[256 + f * 3 + 0] = pB0; cat[256 + f * 3 + 1] = pB1; cat[256 + f * 3 + 2] = pB2;
    }
  }
  __syncthreads();            // cat visible to all

  // ---- fused self-interaction + equivariant activation ----
  if (t < 256) {
    // SI1: 32 outputs x 3 comps; 8 lanes per output, 12 ff-terms each
    const int g = t >> 3, p = t & 7;
    const float* wrow = w_si1 + g * 96 + p * 12;
    const float* c1 = &cat[64 + p * 36];
    float s0 = 0.f, s1 = 0.f, s2 = 0.f;
    #pragma unroll
    for (int k = 0; k < 12; ++k) {
      const float wv = wrow[k];
      s0 = fmaf(c1[k * 3 + 0], wv, s0);
      s1 = fmaf(c1[k * 3 + 1], wv, s1);
      s2 = fmaf(c1[k * 3 + 2], wv, s2);
    }
    s0 += __shfl_xor(s0, 1); s0 += __shfl_xor(s0, 2); s0 += __shfl_xor(s0, 4);
    s1 += __shfl_xor(s1, 1); s1 += __shfl_xor(s1, 2); s1 += __shfl_xor(s1, 4);
    s2 += __shfl_xor(s2, 1); s2 += __shfl_xor(s2, 2); s2 += __shfl_xor(s2, 4);
    if (p == 0) {
      const float n2 = s0 * s0 + s1 * s1 + s2 * s2;
      const float n1 = sqrtf(fmaxf(n2, 1e-7f));     // norm_with_epsilon
      const float a1 = sspf(n1 + b_act1[g]);
      const float sc = a1 / n1;
      const int ob = M_ * A_ * SI_ + (ma * SI_ + g) * 3;
      out[ob + 0] = s0 * sc; out[ob + 1] = s1 * sc; out[ob + 2] = s2 * sc;
    }
  } else if (t < 320) {
    // SI0: 32 outputs; 2 lanes per output, 32 ff-terms each (wave 4 only)
    const int t2 = t - 256, g = t2 >> 1, p = t2 & 1;
    const float* wrow = w_si0 + g * 64 + p * 32;
    const float* c0 = &cat[p * 32];
    float s = 0.f;
    #pragma unroll 8
    for (int k = 0; k < 32; ++k) s = fmaf(c0[k], wrow[k], s);
    s += __shfl_xor(s, 1);
    if (p == 0) out[ma * SI_ + g] = sspf(s + b_act0[g]);
  }
}

extern "C" void kernel_launch(void* const* d_in, const int* in_sizes, int n_in,
                              void* d_out, int out_size, void* d_ws, size_t ws_size,
                              hipStream_t stream) {
  const float* image   = (const float*)d_in[0];
  const float* vectors = (const float*)d_in[1];
  const float* feat0   = (const float*)d_in[2];
  const float* feat1   = (const float*)d_in[3];
  const float* w_si0   = (const float*)d_in[20];
  const float* w_si1   = (const float*)d_in[21];
  const float* b_act0  = (const float*)d_in[22];
  const float* b_act1  = (const float*)d_in[23];
  unsigned short* wsT = (unsigned short*)d_ws;           // 128*64 bf16 = 16384 B
  float* bcw  = (float*)((char*)d_ws + 16384);           // 128 f32
  float* out  = (float*)d_out;

  combine_weights<<<32, 256, 0, stream>>>(
      (const float*)d_in[4],  (const float*)d_in[5],
      (const float*)d_in[6],  (const float*)d_in[7],
      (const float*)d_in[8],  (const float*)d_in[9],
      (const float*)d_in[10], (const float*)d_in[11],
      (const float*)d_in[12], (const float*)d_in[13],
      (const float*)d_in[14], (const float*)d_in[15],
      (const float*)d_in[16], (const float*)d_in[17],
      (const float*)d_in[18], (const float*)d_in[19],
      wsT, bcw);

  conv_fused<<<M_ * A_, 512, 0, stream>>>(
      image, vectors, feat0, feat1, wsT, bcw,
      w_si0, w_si1, b_act0, b_act1, out);
}

// Round 5
// 156.320 us; speedup vs baseline: 1.1188x; 1.0577x over previous
//
#include <hip/hip_runtime.h>
#include <math.h>

#define M_ 4
#define A_ 256
#define RBF_ 64
#define F_ 32
#define H_ 32
#define SI_ 32
#define TF_ 128   // 4 tags * F

typedef __attribute__((ext_vector_type(8))) short bf16x8;
typedef __attribute__((ext_vector_type(4))) float f32x4;
typedef __attribute__((ext_vector_type(3))) float f32x3;

__device__ __forceinline__ unsigned short f2bf(float f) {
  union { float f; unsigned u; } v; v.f = f;
  unsigned r = v.u + 0x7FFFu + ((v.u >> 16) & 1u);   // RNE bf16 (weights, one-time)
  return (unsigned short)(r >> 16);
}

// pack two fp32 -> two bf16 (round-half-up: +0x8000 then take hi16) in 3 VALU
__device__ __forceinline__ unsigned pack2bf(float lo, float hi) {
  union { float f; unsigned u; } a, b; a.f = lo; b.f = hi;
  return __builtin_amdgcn_perm(b.u + 0x8000u, a.u + 0x8000u, 0x07060302u);
}

__device__ __forceinline__ float sspf(float x) {
  // log(0.5*exp(x)+0.5) = softplus(x) - ln2, numerically stable
  return fmaxf(x, 0.f) + log1pf(expf(-fabsf(x))) - 0.6931471805599453f;
}

// ---------------------------------------------------------------------------
// Setup: collapse the two linear Dense layers per tag into one 64x32 map.
// ws layout: WcT bf16 [tf=128][k=64] (16384 B) | bc fp32[128] at +16384.
// tf = tag*32 + f, tag order {00,01,10,11}.
// ---------------------------------------------------------------------------
__global__ __launch_bounds__(256) void combine_weights(
    const float* __restrict__ w1_00, const float* __restrict__ b1_00,
    const float* __restrict__ w2_00, const float* __restrict__ b2_00,
    const float* __restrict__ w1_01, const float* __restrict__ b1_01,
    const float* __restrict__ w2_01, const float* __restrict__ b2_01,
    const float* __restrict__ w1_10, const float* __restrict__ b1_10,
    const float* __restrict__ w2_10, const float* __restrict__ b2_10,
    const float* __restrict__ w1_11, const float* __restrict__ b1_11,
    const float* __restrict__ w2_11, const float* __restrict__ b2_11,
    unsigned short* __restrict__ wsT, float* __restrict__ bcw)
{
  const float* w1s[4] = {w1_00, w1_01, w1_10, w1_11};
  const float* b1s[4] = {b1_00, b1_01, b1_10, b1_11};
  const float* w2s[4] = {w2_00, w2_01, w2_10, w2_11};
  const float* b2s[4] = {b2_00, b2_01, b2_10, b2_11};
  int tid = blockIdx.x * 256 + threadIdx.x;    // 0..8191
  int k   = tid >> 7;
  int tf  = tid & 127;
  int tag = tf >> 5, f = tf & 31;
  const float* w1 = w1s[tag];
  const float* w2 = w2s[tag];
  float s = 0.f;
  for (int h = 0; h < H_; ++h) s += w1[k * H_ + h] * w2[h * F_ + f];
  wsT[tf * 64 + k] = f2bf(s);                  // transposed for B-frag loads
  if (tid < TF_) {
    const float* b1 = b1s[tag];
    const float* b2 = b2s[tag];
    float sb = b2[f];
    for (int h = 0; h < H_; ++h) sb += b1[h] * w2[h * F_ + f];
    bcw[tf] = sb;                              // bias stays fp32
  }
}

// ---------------------------------------------------------------------------
// R16 FUSED kernel: one block per (m,a), grid 1024, 512 thr, 8 waves,
// wave-per-(tag,f-half) role as R13. Staging structure = R13 (proven):
// H1 prologue + H2 one-float4-in-flight stream, 2 lgkm-only barriers.
//  Post-mortem R14/R15: BOTH pipeline-deepening attempts blew the 64-VGPR
//  budget at (512,4) -> scratch spills (18.9 / 8.2 MB stray writes). No
//  register headroom exists for more in-flight state. So R16 reduces the
//  EXPOSED LATENCY per tile instead:
//  The heavy waves (tags 1,3 = half the block) did 12 scalar ds_read_b32
//  of sV inside the fma chain AFTER the MFMA -- at 64-VGPR budget the
//  compiler can't batch them -> fragmented read->wait->use chains set the
//  block critical path. The 12 floats are CONTIGUOUS + 16B-ALIGNED
//  (svc[SOFF..SOFF+11]) -> read as 3x ds_read_b128 issued BEFORE the MFMA
//  so one merged lgkm wait (a-frags + v) covers the whole tile body.
//  4x fewer LDS instrs on critical waves; no loop-carried state added.
//  LDS: sA [256][72] bf16 (36864) + sV[768] f32 (3072, cat overlays) = 39936.
//  Sentinels: VGPR <= ~58 (else void); WRITE_SIZE ~512 KB (spill sentinel).
// ---------------------------------------------------------------------------
__global__ __launch_bounds__(512, 4) void conv_fused(
    const float* __restrict__ image, const float* __restrict__ vectors,
    const float* __restrict__ feat0, const float* __restrict__ feat1,
    const unsigned short* __restrict__ wsT, const float* __restrict__ bcw,
    const float* __restrict__ w_si0, const float* __restrict__ w_si1,
    const float* __restrict__ b_act0, const float* __restrict__ b_act1,
    float* __restrict__ out)
{
  __shared__ __align__(16) unsigned short sA[256 * 72];    // 36864 B
  __shared__ __align__(16) float sV[A_ * 3];               // 3072 B (cat overlays)
  float* const cat = sV;                                   // reused after sync

  const int t    = threadIdx.x;
  const int ma   = blockIdx.x;      // m*256 + a
  const int m    = ma >> 8;
  const int l    = t & 63;
  const int n    = l & 15;
  const int quad = l >> 4;
  // wave id as SGPR -> uniform branches; rotate roles across SIMDs per block
  const int wu    = __builtin_amdgcn_readfirstlane(t >> 6);   // 0..7
  const int role  = (wu + ((ma & 3) << 1)) & 7;
  const int which = role & 1;
  const int tag   = role >> 1;      // 0:'00' 1:'01' 2:'10' 3:'11'
  const int ct    = tag * 2 + which;
  const int f     = which * 16 + n; // feature column this lane owns

  // ---- Wc fragment + bias into registers (global, L2-resident) ----
  const unsigned short* wr = wsT + (ct * 16 + n) * 64 + quad * 8;
  const bf16x8 w0 = *(const bf16x8*)(wr);
  const bf16x8 w1 = *(const bf16x8*)(wr + 32);
  const float  bc = bcw[ct * 16 + n];

  // ---- stage addressing: thread t owns row t>>2 (0..127), cols (t&3)*16 ----
  const int srow = t >> 2;
  const int sc16 = (t & 3) << 4;
  const float* g1 = image + (size_t)ma * (A_ * RBF_) + srow * RBF_ + sc16;
  const float* g2 = g1 + 128 * RBF_;                 // H2 source (rows +128)
  unsigned short* w1p = &sA[srow * 72 + sc16];
  unsigned short* w2p = &sA[(srow + 128) * 72 + sc16];

  // ---- H1: 4 float4 loads, pack, two b128 LDS writes ----
  float4 a0 = *(const float4*)(g1);
  float4 a1 = *(const float4*)(g1 + 4);
  float4 a2 = *(const float4*)(g1 + 8);
  float4 a3 = *(const float4*)(g1 + 12);
  // ---- stage vectors (256 b x 3) to LDS ----
  {
    const float* vsrc = vectors + (size_t)ma * (A_ * 3);
    sV[t] = vsrc[t];
    if (t < 256) sV[t + 512] = vsrc[t + 512];
  }
  {
    uint4 pk;
    pk.x = pack2bf(a0.x, a0.y); pk.y = pack2bf(a0.z, a0.w);
    pk.z = pack2bf(a1.x, a1.y); pk.w = pack2bf(a1.z, a1.w);
    *(uint4*)w1p = pk;
    pk.x = pack2bf(a2.x, a2.y); pk.y = pack2bf(a2.z, a2.w);
    pk.z = pack2bf(a3.x, a3.y); pk.w = pack2bf(a3.z, a3.w);
    *(uint4*)(w1p + 8) = pk;
  }
  // first H2 quarter in flight across the barrier
  float4 hb = *(const float4*)(g2);

  // ---- running feat pointers (advanced by constants; imm-offset loads) ----
  const int b0q = quad * 4;
  const float* p0c = feat0 + (size_t)(m * A_ + b0q) * F_ + f;       // feat0 col
  const float* p1c = feat1 + ((size_t)(m * A_ + b0q) * F_ + f) * 3; // feat1 col
  const float* svc = &sV[b0q * 3];
  const unsigned short* aBc = &sA[n * 72 + quad * 8];

  float gx[2][4], gy[2][4], gz[2][4];
  float pA = 0.f, pB0 = 0.f, pB1 = 0.f, pB2 = 0.f;

#define PF(BUF) { \
    if (tag <= 1) { \
      _Pragma("unroll") \
      for (int r = 0; r < 4; ++r) gx[BUF][r] = p0c[r * F_]; \
    } else { \
      _Pragma("unroll") \
      for (int r = 0; r < 4; ++r) { \
        f32x3 v = *(const f32x3*)(p1c + r * (F_ * 3)); \
        gx[BUF][r] = v[0]; gy[BUF][r] = v[1]; gz[BUF][r] = v[2]; \
      } \
    } \
    p0c += 16 * F_; p1c += 16 * F_ * 3; }

  // Tile body. v-needing waves (tags 1,3) read their quad's 12 contiguous
  // sV floats as 3x ds_read_b128 BEFORE the MFMA: one merged lgkm wait
  // covers a-frags + v; contraction then runs from registers.
  // flat idx r*3+c -> v0[0..3]=idx0..3, v1[0..3]=idx4..7, v2[0..3]=idx8..11.
#define BODY(AOFF, SOFF, GX, GY, GZ) { \
    const bf16x8 a0_ = *(const bf16x8*)(aBc + (AOFF)); \
    const bf16x8 a1_ = *(const bf16x8*)(aBc + (AOFF) + 32); \
    f32x4 v0, v1, v2; \
    if (tag & 1) { \
      v0 = *(const f32x4*)(svc + (SOFF)); \
      v1 = *(const f32x4*)(svc + (SOFF) + 4); \
      v2 = *(const f32x4*)(svc + (SOFF) + 8); \
    } \
    f32x4 acc = {bc, bc, bc, bc}; \
    acc = __builtin_amdgcn_mfma_f32_16x16x32_bf16(a0_, w0, acc, 0, 0, 0); \
    acc = __builtin_amdgcn_mfma_f32_16x16x32_bf16(a1_, w1, acc, 0, 0, 0); \
    if (tag == 0) {            /* out_0x0_0 */ \
      _Pragma("unroll") \
      for (int r = 0; r < 4; ++r) pA += acc[r] * GX[r]; \
    } else if (tag == 1) {     /* out_0x1_1 = v * (R*feat0) */ \
      float s; \
      s = acc[0] * GX[0]; \
      pB0 = fmaf(v0[0], s, pB0); pB1 = fmaf(v0[1], s, pB1); pB2 = fmaf(v0[2], s, pB2); \
      s = acc[1] * GX[1]; \
      pB0 = fmaf(v0[3], s, pB0); pB1 = fmaf(v1[0], s, pB1); pB2 = fmaf(v1[1], s, pB2); \
      s = acc[2] * GX[2]; \
      pB0 = fmaf(v1[2], s, pB0); pB1 = fmaf(v1[3], s, pB1); pB2 = fmaf(v2[0], s, pB2); \
      s = acc[3] * GX[3]; \
      pB0 = fmaf(v2[1], s, pB0); pB1 = fmaf(v2[2], s, pB1); pB2 = fmaf(v2[3], s, pB2); \
    } else if (tag == 2) {     /* out_1x0_1 = R * feat1 */ \
      _Pragma("unroll") \
      for (int r = 0; r < 4; ++r) { \
        const float Rr = acc[r]; \
        pB0 += Rr * GX[r]; pB1 += Rr * GY[r]; pB2 += Rr * GZ[r]; \
      } \
    } else {                   /* out_1x1_0 (dot) + out_1x1_1 (cross) */ \
      { const float Rr = acc[0], ax = GX[0], ay = GY[0], az = GZ[0]; \
        const float vx = v0[0], vy = v0[1], vz = v0[2]; \
        float d = vx * ax; d = fmaf(vy, ay, d); d = fmaf(vz, az, d); \
        pA = fmaf(Rr, d, pA); \
        float c0 = vy * az; c0 = fmaf(-vz, ay, c0); pB0 = fmaf(Rr, c0, pB0); \
        float c1 = vz * ax; c1 = fmaf(-vx, az, c1); pB1 = fmaf(Rr, c1, pB1); \
        float c2 = vx * ay; c2 = fmaf(-vy, ax, c2); pB2 = fmaf(Rr, c2, pB2); } \
      { const float Rr = acc[1], ax = GX[1], ay = GY[1], az = GZ[1]; \
        const float vx = v0[3], vy = v1[0], vz = v1[1]; \
        float d = vx * ax; d = fmaf(vy, ay, d); d = fmaf(vz, az, d); \
        pA = fmaf(Rr, d, pA); \
        float c0 = vy * az; c0 = fmaf(-vz, ay, c0); pB0 = fmaf(Rr, c0, pB0); \
        float c1 = vz * ax; c1 = fmaf(-vx, az, c1); pB1 = fmaf(Rr, c1, pB1); \
        float c2 = vx * ay; c2 = fmaf(-vy, ax, c2); pB2 = fmaf(Rr, c2, pB2); } \
      { const float Rr = acc[2], ax = GX[2], ay = GY[2], az = GZ[2]; \
        const float vx = v1[2], vy = v1[3], vz = v2[0]; \
        float d = vx * ax; d = fmaf(vy, ay, d); d = fmaf(vz, az, d); \
        pA = fmaf(Rr, d, pA); \
        float c0 = vy * az; c0 = fmaf(-vz, ay, c0); pB0 = fmaf(Rr, c0, pB0); \
        float c1 = vz * ax; c1 = fmaf(-vx, az, c1); pB1 = fmaf(Rr, c1, pB1); \
        float c2 = vx * ay; c2 = fmaf(-vy, ax, c2); pB2 = fmaf(Rr, c2, pB2); } \
      { const float Rr = acc[3], ax = GX[3], ay = GY[3], az = GZ[3]; \
        const float vx = v2[1], vy = v2[2], vz = v2[3]; \
        float d = vx * ax; d = fmaf(vy, ay, d); d = fmaf(vz, az, d); \
        pA = fmaf(Rr, d, pA); \
        float c0 = vy * az; c0 = fmaf(-vz, ay, c0); pB0 = fmaf(Rr, c0, pB0); \
        float c1 = vz * ax; c1 = fmaf(-vx, az, c1); pB1 = fmaf(Rr, c1, pB1); \
        float c2 = vx * ay; c2 = fmaf(-vy, ax, c2); pB2 = fmaf(Rr, c2, pB2); } \
    } }

  // H2 stream: pack the in-flight quarter, (optionally) issue the next
#define H2PACK_R() { \
    uint2 pk; pk.x = pack2bf(hb.x, hb.y); pk.y = pack2bf(hb.z, hb.w); \
    *(uint2*)w2p = pk; w2p += 4; \
    g2 += 4; hb = *(const float4*)(g2); }
#define H2PACK_F() { \
    uint2 pk; pk.x = pack2bf(hb.x, hb.y); pk.y = pack2bf(hb.z, hb.w); \
    *(uint2*)w2p = pk; }

  // lgkm-only barrier: ds ops drained, global loads STAY IN FLIGHT.
#define BARRIER() { \
    asm volatile("s_waitcnt lgkmcnt(0)" ::: "memory"); \
    __builtin_amdgcn_s_barrier(); \
    asm volatile("" ::: "memory"); }

  PF(0)                                 // feat tile 0 (in flight over barrier)
  BARRIER();

  // ---- tiles 0..7 (H1 rows), H2 stream interleaved: 1 f4 in flight ----
  #pragma unroll 1
  for (int d = 0; d < 4; ++d) {
    PF(1)                                               // feat tile 2d+1
    BODY(0, 0, gx[0], gy[0], gz[0])                     // tile 2d
    PF(0)                                               // feat tile 2d+2
    BODY(1152, 48, gx[1], gy[1], gz[1])                 // tile 2d+1
    aBc += 2304; svc += 96;
    // pack the in-flight H2 quarter (vmcnt waits hb; ~2 tiles of lead)
    { uint2 pk; pk.x = pack2bf(hb.x, hb.y); pk.y = pack2bf(hb.z, hb.w);
      *(uint2*)w2p = pk; }
    w2p += 4;
    if (d < 3) { g2 += 4; hb = *(const float4*)(g2); }  // issue next quarter
  }
  BARRIER();                            // H2 ds_writes drained; rows 128+ ready

  // ---- tiles 8..15: straight-line, zero syncs ----
  #pragma unroll 1
  for (int d = 0; d < 4; ++d) {
    PF(1)                                               // feat tile 2d+9
    BODY(0, 0, gx[0], gy[0], gz[0])                     // tile 2d+8
    if (d < 3) PF(0)                                    // feat tile 2d+10
    BODY(1152, 48, gx[1], gy[1], gz[1])                 // tile 2d+9
    aBc += 2304; svc += 96;
  }

  // ---- reduce the 4 quad-copies ----
#define QRED(x) { x += __shfl_xor(x, 16); x += __shfl_xor(x, 32); }
  QRED(pA) QRED(pB0) QRED(pB1) QRED(pB2)
  __syncthreads();            // all sV reads done (cat overlays sV)
  if (quad == 0) {
    // slots (cat order): out000: f | out110: 32+f | out011: 64+f*3+d
    //                    out101: 160+f*3+d | out111: 256+f*3+d
    if (tag == 0) {
      cat[f] = pA;
    } else if (tag == 1) {
      cat[64 + f * 3 + 0] = pB0; cat[64 + f * 3 + 1] = pB1; cat[64 + f * 3 + 2] = pB2;
    } else if (tag == 2) {
      cat[160 + f * 3 + 0] = pB0; cat[160 + f * 3 + 1] = pB1; cat[160 + f * 3 + 2] = pB2;
    } else {
      cat[32 + f] = pA;
      cat[256 + f * 3 + 0] = pB0; cat[256 + f * 3 + 1] = pB1; cat[256 + f * 3 + 2] = pB2;
    }
  }
  __syncthreads();            // cat visible to all

  // ---- fused self-interaction + equivariant activation ----
  if (t < 256) {
    // SI1: 32 outputs x 3 comps; 8 lanes per output, 12 ff-terms each
    const int g = t >> 3, p = t & 7;
    const float* wrow = w_si1 + g * 96 + p * 12;
    const float* c1 = &cat[64 + p * 36];
    float s0 = 0.f, s1 = 0.f, s2 = 0.f;
    #pragma unroll
    for (int k = 0; k < 12; ++k) {
      const float wv = wrow[k];
      s0 = fmaf(c1[k * 3 + 0], wv, s0);
      s1 = fmaf(c1[k * 3 + 1], wv, s1);
      s2 = fmaf(c1[k * 3 + 2], wv, s2);
    }
    s0 += __shfl_xor(s0, 1); s0 += __shfl_xor(s0, 2); s0 += __shfl_xor(s0, 4);
    s1 += __shfl_xor(s1, 1); s1 += __shfl_xor(s1, 2); s1 += __shfl_xor(s1, 4);
    s2 += __shfl_xor(s2, 1); s2 += __shfl_xor(s2, 2); s2 += __shfl_xor(s2, 4);
    if (p == 0) {
      const float n2 = s0 * s0 + s1 * s1 + s2 * s2;
      const float n1 = sqrtf(fmaxf(n2, 1e-7f));     // norm_with_epsilon
      const float a1 = sspf(n1 + b_act1[g]);
      const float sc = a1 / n1;
      const int ob = M_ * A_ * SI_ + (ma * SI_ + g) * 3;
      out[ob + 0] = s0 * sc; out[ob + 1] = s1 * sc; out[ob + 2] = s2 * sc;
    }
  } else if (t < 320) {
    // SI0: 32 outputs; 2 lanes per output, 32 ff-terms each (wave 4 only)
    const int t2 = t - 256, g = t2 >> 1, p = t2 & 1;
    const float* wrow = w_si0 + g * 64 + p * 32;
    const float* c0 = &cat[p * 32];
    float s = 0.f;
    #pragma unroll 8
    for (int k = 0; k < 32; ++k) s = fmaf(c0[k], wrow[k], s);
    s += __shfl_xor(s, 1);
    if (p == 0) out[ma * SI_ + g] = sspf(s + b_act0[g]);
  }
}

extern "C" void kernel_launch(void* const* d_in, const int* in_sizes, int n_in,
                              void* d_out, int out_size, void* d_ws, size_t ws_size,
                              hipStream_t stream) {
  const float* image   = (const float*)d_in[0];
  const float* vectors = (const float*)d_in[1];
  const float* feat0   = (const float*)d_in[2];
  const float* feat1   = (const float*)d_in[3];
  const float* w_si0   = (const float*)d_in[20];
  const float* w_si1   = (const float*)d_in[21];
  const float* b_act0  = (const float*)d_in[22];
  const float* b_act1  = (const float*)d_in[23];
  unsigned short* wsT = (unsigned short*)d_ws;           // 128*64 bf16 = 16384 B
  float* bcw  = (float*)((char*)d_ws + 16384);           // 128 f32
  float* out  = (float*)d_out;

  combine_weights<<<32, 256, 0, stream>>>(
      (const float*)d_in[4],  (const float*)d_in[5],
      (const float*)d_in[6],  (const float*)d_in[7],
      (const float*)d_in[8],  (const float*)d_in[9],
      (const float*)d_in[10], (const float*)d_in[11],
      (const float*)d_in[12], (const float*)d_in[13],
      (const float*)d_in[14], (const float*)d_in[15],
      (const float*)d_in[16], (const float*)d_in[17],
      (const float*)d_in[18], (const float*)d_in[19],
      wsT, bcw);

  conv_fused<<<M_ * A_, 512, 0, stream>>>(
      image, vectors, feat0, feat1, wsT, bcw,
      w_si0, w_si1, b_act0, b_act1, out);
}